// Round 4
// baseline (240.725 us; speedup 1.0000x reference)
//
#include <hip/hip_runtime.h>

// Correlation layer: out[b,o,h,w] = mean_c x1[b,c,h,w] * x2[b,c,h+dh,w+dw]
// B=8 C=128 H=W=128, d=4 -> 81 offsets (o = (dh+4)*9 + (dw+4)).
//
// R4 vs R3 (88 us): R3's acc[3][9] float4 = 108 f32 accs forced the compiler
// to park accs in AGPRs (VGPR_Count=80 < live set!) and shuttle with
// v_accvgpr_read/write around every FMA -> hidden VALU tax was the wall.
//  - 8 px/thread x 9 dw (one dh per WG) = 72 accs, fits in VGPRs
//  - better LDS ratio: 4 ds_read_b128 (16-float window) per 72 FMA
//  - 1 wave per WG, wave-private staging (4 x2 rows, no row halo), ZERO
//    barriers; no c-split -> no reduction epilogue
//  - grid 8b x 9dh x 32 rowblocks = 2304 WGs = 9 waves/CU, XCD swizzle

constexpr int Bn = 8, Cn = 128, Hn = 128, Wn = 128;
constexpr int HWn = Hn * Wn;
constexpr int ROWF = 136;   // staged row: cols -4..131 at idx 0..135 (34 float4)
constexpr int NSLOT = 4 * 34; // 136 float4 staging slots

__global__ __launch_bounds__(64, 3)
void corr_kernel(const float* __restrict__ x1, const float* __restrict__ x2,
                 float* __restrict__ out) {
  __shared__ float s2[4 * ROWF];      // wave-private (1 wave/WG), 2176 B

  const int lane = threadIdx.x;       // 0..63
  const int rl   = lane >> 4;         // local out row 0..3
  const int px0  = (lane & 15) << 3;  // 0,8,...,120

  // --- XCD swizzle: batch b on XCD b (round-robin assumption; perf-only) ---
  const int phys = blockIdx.x;        // 0..2303
  const int b    = phys & 7;
  const int slot = phys >> 3;         // 0..287
  const int dh   = slot % 9 - 4;      // -4..4
  const int h0   = (slot / 9) * 4;    // row block base

  // --- staging slots (lane-linear): s = lane, lane+64, lane+128(<136) ---
  const int s0i = lane, s1i = lane + 64, s2i = lane + 128;
  const bool act2 = (lane < NSLOT - 128);          // lanes 0..7
  const int sr0 = s0i / 34, fc0 = s0i % 34;
  const int sr1 = s1i / 34, fc1 = s1i % 34;
  const int sr2 = act2 ? s2i / 34 : 0, fc2 = act2 ? s2i % 34 : 0;
  const int gr0 = h0 + sr0 + dh, gr1 = h0 + sr1 + dh, gr2 = h0 + sr2 + dh;
  const bool ok0 = ((unsigned)gr0 < (unsigned)Hn) && (fc0 >= 1) && (fc0 <= 32);
  const bool ok1 = ((unsigned)gr1 < (unsigned)Hn) && (fc1 >= 1) && (fc1 <= 32);
  const bool ok2 = act2 && ((unsigned)gr2 < (unsigned)Hn) && (fc2 >= 1) && (fc2 <= 32);
  const int off0 = gr0 * Wn + fc0 * 4 - 4;
  const int off1 = gr1 * Wn + fc1 * 4 - 4;
  const int off2 = gr2 * Wn + fc2 * 4 - 4;
  float* lp0 = &s2[sr0 * ROWF + fc0 * 4];
  float* lp1 = &s2[sr1 * ROWF + fc1 * 4];
  float* lp2 = &s2[sr2 * ROWF + fc2 * 4];
  const float* srow = &s2[rl * ROWF + px0];  // window idx px0 == col px0-4

  const float* x1c = x1 + (size_t)b * Cn * HWn + (h0 + rl) * Wn + px0;
  const float* x2c = x2 + (size_t)b * Cn * HWn;

  float4 acc[9][2];
#pragma unroll
  for (int dw = 0; dw < 9; ++dw) {
    acc[dw][0] = make_float4(0.f, 0.f, 0.f, 0.f);
    acc[dw][1] = make_float4(0.f, 0.f, 0.f, 0.f);
  }

  // --- prologue: prefetch channel 0 (halo lanes keep zeros forever) ---
  float4 pv0 = make_float4(0.f, 0.f, 0.f, 0.f);
  float4 pv1 = make_float4(0.f, 0.f, 0.f, 0.f);
  float4 pv2 = make_float4(0.f, 0.f, 0.f, 0.f);
  if (ok0) pv0 = *(const float4*)(x2c + off0);
  if (ok1) pv1 = *(const float4*)(x2c + off1);
  if (ok2) pv2 = *(const float4*)(x2c + off2);
  float4 pa0 = *(const float4*)(x1c);
  float4 pa1 = *(const float4*)(x1c + 4);

#pragma unroll 1
  for (int cc = 0; cc < 128; ++cc) {
    // stage channel cc (regs prefetched last iter)
    *(float4*)lp0 = pv0;
    *(float4*)lp1 = pv1;
    if (act2) *(float4*)lp2 = pv2;
    const float4 a0 = pa0, a1 = pa1;
    // prefetch channel cc+1 (covers load latency with this iter's compute)
    if (cc < 127) {
      const float* nx2 = x2c + (size_t)(cc + 1) * HWn;
      if (ok0) pv0 = *(const float4*)(nx2 + off0);
      if (ok1) pv1 = *(const float4*)(nx2 + off1);
      if (ok2) pv2 = *(const float4*)(nx2 + off2);
      const float* nx1 = x1c + (size_t)(cc + 1) * HWn;
      pa0 = *(const float4*)(nx1);
      pa1 = *(const float4*)(nx1 + 4);
    }
    // window: 16 floats = 4 b128; wave-private + DS in-order => no barrier
    const float4 w0 = *(const float4*)(srow);
    const float4 w1 = *(const float4*)(srow + 4);
    const float4 w2 = *(const float4*)(srow + 8);
    const float4 w3 = *(const float4*)(srow + 12);
    const float win[16] = {w0.x, w0.y, w0.z, w0.w, w1.x, w1.y, w1.z, w1.w,
                           w2.x, w2.y, w2.z, w2.w, w3.x, w3.y, w3.z, w3.w};
    const float av[8] = {a0.x, a0.y, a0.z, a0.w, a1.x, a1.y, a1.z, a1.w};
    // pixel j (0..7) with offset dw-4 reads win[j+dw]
#pragma unroll
    for (int dw = 0; dw < 9; ++dw) {
      acc[dw][0].x += av[0] * win[dw + 0];
      acc[dw][0].y += av[1] * win[dw + 1];
      acc[dw][0].z += av[2] * win[dw + 2];
      acc[dw][0].w += av[3] * win[dw + 3];
      acc[dw][1].x += av[4] * win[dw + 4];
      acc[dw][1].y += av[5] * win[dw + 5];
      acc[dw][1].z += av[6] * win[dw + 6];
      acc[dw][1].w += av[7] * win[dw + 7];
    }
  }

  // --- store: 9 dw planes x 8 px ---
  const float scale = 1.0f / 128.0f;
  const int obase = (dh + 4) * 9;
  float* ob = out + ((size_t)b * 81 + obase) * HWn + (size_t)(h0 + rl) * Wn + px0;
#pragma unroll
  for (int dw = 0; dw < 9; ++dw) {
    float4 lo = acc[dw][0], hi = acc[dw][1];
    lo.x *= scale; lo.y *= scale; lo.z *= scale; lo.w *= scale;
    hi.x *= scale; hi.y *= scale; hi.z *= scale; hi.w *= scale;
    *(float4*)(ob + (size_t)dw * HWn)     = lo;
    *(float4*)(ob + (size_t)dw * HWn + 4) = hi;
  }
}

extern "C" void kernel_launch(void* const* d_in, const int* in_sizes, int n_in,
                              void* d_out, int out_size, void* d_ws, size_t ws_size,
                              hipStream_t stream) {
  const float* x1 = (const float*)d_in[0];
  const float* x2 = (const float*)d_in[1];
  float* out = (float*)d_out;
  const int n_wgs = Bn * 9 * (Hn / 4);  // 2304 = 9 waves/CU
  corr_kernel<<<dim3(n_wgs), dim3(64), 0, stream>>>(x1, x2, out);
}

// Round 5
// 193.209 us; speedup vs baseline: 1.2459x; 1.2459x over previous
//
#include <hip/hip_runtime.h>

// Correlation layer: out[b,o,h,w] = mean_c x1[b,c,h,w] * x2[b,c,h+dh,w+dw]
// B=8 C=128 H=W=128, d=4 -> 81 offsets (o = (dh+4)*9 + (dw+4)).
//
// R5: ZERO-LDS design. R4 post-mortem: VALU issue is ~27 us in every round;
// the wall is the staging->LDS->window chain (+ bank conflicts in R4: lane
// stride 8 floats => 16/32 banks). Key insight: with 8 px/thread one image
// row = 16 lanes = one DPP row, and row_shr:1 / row_shl:1 zero-fill at DPP
// row edges IS the correlation zero-pad. So the x2 window lives entirely in
// registers: 2 float4 own-loads + 8 DPP movs. No LDS, no barriers, no halo.
//  - dh pairing: groups 0-3: wave = 2 rows x 2 dh (lanes>>5 picks dh);
//    group 4: wave = 4 rows x dh=+4. 72 accs/thread everywhere.
//  - 2-deep register prefetch (~2 iters =~900 cyc slack) hides L3/HBM latency
//  - grid 8b x 288 = 2304 single-wave WGs = 9 waves/CU, batch-per-XCD swizzle

constexpr int Bn = 8, Cn = 128, Hn = 128, Wn = 128;
constexpr int HWn = Hn * Wn;

__device__ __forceinline__ float dpp_from_lower(float x) {
  // lane i <- lane i-1 within 16-lane row (row_shr:1), 0 at row start
  return __int_as_float(
      __builtin_amdgcn_update_dpp(0, __float_as_int(x), 0x111, 0xF, 0xF, true));
}
__device__ __forceinline__ float dpp_from_upper(float x) {
  // lane i <- lane i+1 within 16-lane row (row_shl:1), 0 at row end
  return __int_as_float(
      __builtin_amdgcn_update_dpp(0, __float_as_int(x), 0x101, 0xF, 0xF, true));
}

__global__ __launch_bounds__(64, 3)
void corr_kernel(const float* __restrict__ x1, const float* __restrict__ x2,
                 float* __restrict__ out) {
  const int lane = threadIdx.x;       // 0..63
  const int j    = lane & 15;         // position within image row
  const int px0  = j << 3;            // 0,8,...,120

  // --- XCD swizzle: batch b on XCD b (round-robin assumption; perf-only) ---
  const int phys = blockIdx.x;        // 0..2303
  const int b    = phys & 7;
  const int s    = phys >> 3;         // 0..287
  int rowl, dh;
  if (s < 256) {                      // dh pairs: (2g-4, 2g-3), 2 rows/wave
    const int g = s >> 6;             // 0..3
    const int t = s & 63;             // row-pair index
    rowl = (t << 1) + ((lane >> 4) & 1);
    dh   = (g << 1) - 4 + (lane >> 5);
  } else {                            // dh = +4, 4 rows/wave
    const int t = s - 256;            // 0..31
    rowl = (t << 2) + (lane >> 4);
    dh   = 4;
  }
  const int x2row = rowl + dh;
  const bool ok = ((unsigned)x2row < (unsigned)Hn);  // per-lane, loop-invariant

  const float* x1p = x1 + (size_t)b * Cn * HWn + rowl * Wn + px0;
  const float* x2p = x2 + (size_t)b * Cn * HWn + x2row * Wn + px0;

  float4 acc[9][2];
#pragma unroll
  for (int dw = 0; dw < 9; ++dw) {
    acc[dw][0] = make_float4(0.f, 0.f, 0.f, 0.f);
    acc[dw][1] = make_float4(0.f, 0.f, 0.f, 0.f);
  }

  const float4 fz = make_float4(0.f, 0.f, 0.f, 0.f);
  float4 A[2][2], B[2][2];
  // --- prologue: load channels 0 and 1 into slots 0,1 ---
#pragma unroll
  for (int p = 0; p < 2; ++p) {
    const float* xp = x1p + (size_t)p * HWn;
    A[p][0] = *(const float4*)xp;
    A[p][1] = *(const float4*)(xp + 4);
    float4 t0 = fz, t1 = fz;
    if (ok) {
      const float* yp = x2p + (size_t)p * HWn;
      t0 = *(const float4*)yp;
      t1 = *(const float4*)(yp + 4);
    }
    B[p][0] = t0;
    B[p][1] = t1;
  }
  const float* pf1 = x1p + 2 * (size_t)HWn;
  const float* pf2 = x2p + 2 * (size_t)HWn;

#pragma unroll 2
  for (int cc = 0; cc < 128; ++cc) {
    const int sl = cc & 1;
    const float4 a0 = A[sl][0], a1 = A[sl][1];
    const float4 b0 = B[sl][0], b1 = B[sl][1];
    // prefetch channel cc+2 into the slot just freed (2-iter latency slack)
    if (cc < 126) {
      A[sl][0] = *(const float4*)pf1;
      A[sl][1] = *(const float4*)(pf1 + 4);
      float4 t0 = fz, t1 = fz;
      if (ok) {
        t0 = *(const float4*)pf2;
        t1 = *(const float4*)(pf2 + 4);
      }
      B[sl][0] = t0;
      B[sl][1] = t1;
      pf1 += HWn;
      pf2 += HWn;
    }
    // window cols px0-4..px0+11 in registers: neighbors via DPP, 0 at edges
    const float p4 = dpp_from_lower(b1.x);  // col px0-4
    const float p5 = dpp_from_lower(b1.y);
    const float p6 = dpp_from_lower(b1.z);
    const float p7 = dpp_from_lower(b1.w);
    const float n0 = dpp_from_upper(b0.x);  // col px0+8
    const float n1 = dpp_from_upper(b0.y);
    const float n2 = dpp_from_upper(b0.z);
    const float n3 = dpp_from_upper(b0.w);
    const float win[16] = {p4, p5, p6, p7, b0.x, b0.y, b0.z, b0.w,
                           b1.x, b1.y, b1.z, b1.w, n0, n1, n2, n3};
    const float av[8] = {a0.x, a0.y, a0.z, a0.w, a1.x, a1.y, a1.z, a1.w};
    // pixel jj (0..7) with offset dw-4 reads win[jj+dw]
#pragma unroll
    for (int dw = 0; dw < 9; ++dw) {
      acc[dw][0].x += av[0] * win[dw + 0];
      acc[dw][0].y += av[1] * win[dw + 1];
      acc[dw][0].z += av[2] * win[dw + 2];
      acc[dw][0].w += av[3] * win[dw + 3];
      acc[dw][1].x += av[4] * win[dw + 4];
      acc[dw][1].y += av[5] * win[dw + 5];
      acc[dw][1].z += av[6] * win[dw + 6];
      acc[dw][1].w += av[7] * win[dw + 7];
    }
  }

  // --- store: 9 dw planes x 8 px (one row, one dh per thread) ---
  const float scale = 1.0f / 128.0f;
  const int obase = (dh + 4) * 9;
  float* ob = out + ((size_t)b * 81 + obase) * HWn + (size_t)rowl * Wn + px0;
#pragma unroll
  for (int dw = 0; dw < 9; ++dw) {
    float4 lo = acc[dw][0], hi = acc[dw][1];
    lo.x *= scale; lo.y *= scale; lo.z *= scale; lo.w *= scale;
    hi.x *= scale; hi.y *= scale; hi.z *= scale; hi.w *= scale;
    *(float4*)(ob + (size_t)dw * HWn)     = lo;
    *(float4*)(ob + (size_t)dw * HWn + 4) = hi;
  }
}

extern "C" void kernel_launch(void* const* d_in, const int* in_sizes, int n_in,
                              void* d_out, int out_size, void* d_ws, size_t ws_size,
                              hipStream_t stream) {
  const float* x1 = (const float*)d_in[0];
  const float* x2 = (const float*)d_in[1];
  float* out = (float*)d_out;
  const int n_wgs = Bn * (4 * 64 + 32);  // 2304 = 9 waves/CU
  corr_kernel<<<dim3(n_wgs), dim3(64), 0, stream>>>(x1, x2, out);
}